// Round 22
// baseline (105.967 us; speedup 1.0000x reference)
//
#include <hip/hip_runtime.h>

#define DEVI __device__ __forceinline__

typedef int i32x4 __attribute__((ext_vector_type(4)));

static constexpr int Bdim = 2048;
static constexpr int Kdim = 4096;
static constexpr int Ndim = 8192;
static constexpr int BK   = 128;         // int8 k-elements per tile (128 B/row)
static constexpr int NT   = Kdim / BK;   // 32 K-tiles

typedef __attribute__((address_space(1))) const unsigned int gas_t;
typedef __attribute__((address_space(3))) unsigned int las_t;

DEVI void gload_lds16(const void* g, void* l) {
    __builtin_amdgcn_global_load_lds((gas_t*)g, (las_t*)l, 16, 0, 0);
}

DEVI int pack4(i32x4 v) {
    return (v[0] & 255) | ((v[1] & 255) << 8) | ((v[2] & 255) << 16) | (v[3] << 24);
}

// ------------- pack both inputs, one launch (block-aligned split) -------------
__global__ void pack_all(const int* __restrict__ x32, const int* __restrict__ w32,
                         char* __restrict__ xa, char* __restrict__ wa,
                         int nx16, int ntot) {
    int i = blockIdx.x * blockDim.x + threadIdx.x;
    if (i >= ntot) return;
    const int* src;
    char* dst;
    if (i < nx16) { src = x32 + (size_t)i * 16;          dst = xa + (size_t)i * 16; }
    else          { src = w32 + (size_t)(i - nx16) * 16; dst = wa + (size_t)(i - nx16) * 16; }
    const i32x4* s4 = (const i32x4*)src;
    i32x4 r;
    r[0] = pack4(s4[0]);
    r[1] = pack4(s4[1]);
    r[2] = pack4(s4[2]);
    r[3] = pack4(s4[3]);
    *(i32x4*)dst = r;
}

// -------- 256x256 i8 GEMM: fence-free read||MFMA interleave, FULL reg budget --------
// r12 structure + amdgpu_waves_per_eu(2,2): the only untested cell of the
// {schedule} x {register budget} matrix. Reads for the NEXT quadrant issue
// between MFMA clusters; compiler emits per-fragment counted lgkmcnt.
#define CFENCE asm volatile("" ::: "memory")
DEVI void bar() { CFENCE; __builtin_amdgcn_s_barrier(); CFENCE; }
#define WAITVM(N) asm volatile("s_waitcnt vmcnt(" #N ")" ::: "memory")

#define QUAD(MB, A, B)                                                           \
    do {                                                                         \
        _Pragma("unroll") for (int mm = 0; mm < 4; ++mm)                         \
        _Pragma("unroll") for (int n = 0; n < 4; ++n)                            \
            acc[(MB) + mm][n] = __builtin_amdgcn_mfma_i32_16x16x64_i8(           \
                (A)[mm], (B)[n], acc[(MB) + mm][n], 0, 0, 0);                    \
    } while (0)

#define LD_A(DST, BUF, KS, H)                                                    \
    _Pragma("unroll") for (int mm = 0; mm < 4; ++mm) (DST)[mm] = rdA(BUF, KS, (H) + mm)
#define LD_B(DST, BUF, KS)                                                       \
    _Pragma("unroll") for (int n = 0; n < 4; ++n) (DST)[n] = rdB(BUF, KS, n)

__attribute__((amdgpu_waves_per_eu(2, 2)))
__global__ __launch_bounds__(512, 2)
void gemm22(const char* __restrict__ A8, const char* __restrict__ B8,
            const int* __restrict__ bias,
            const int* __restrict__ qm_p, const int* __restrict__ ex_p,
            const int* __restrict__ zp_p, int* __restrict__ out) {
    // LDS (16B units): A [2 buf][2 ks][256 rows][4 slots] at 0, B same at 4096
    __shared__ i32x4 smem4[8192];                     // 128 KiB
    char* smem = (char*)smem4;

    const int tid  = threadIdx.x;
    const int wid  = tid >> 6;
    const int lane = tid & 63;
    const int l15  = lane & 15;
    const int lks  = lane >> 4;
    const int wr   = wid >> 2;   // 0..1
    const int wc   = wid & 3;    // 0..3

    // XCD-bijective swizzle (256 % 8 == 0)
    const int bid = blockIdx.x;
    const int swz = (bid & 7) * 32 + (bid >> 3);
    const int bm  = swz >> 5;    // 0..7
    const int bn  = swz & 31;    // 0..31
    const int arow0 = bm * 256;
    const int brow0 = bn * 256;

    // T2 swizzle (r10-verified 0-conflict): phys slot = chunk ^ ((row>>1)&3)
    const int swsel = lks ^ ((l15 >> 1) & 3);
    const int a_rd16 = (wr * 128 + l15) * 4 + swsel;
    const int b_rd16 = 4096 + (wc * 64 + l15) * 4 + swsel;

    // staging: thread covers rows tid>>2 (+128), chunk st_c (inverse swizzle)
    const int st_c = (tid & 3) ^ ((tid >> 3) & 3);
    const char* agp = A8 + (size_t)(arow0 + (tid >> 2)) * Kdim + st_c * 16;
    const char* bgp = B8 + (size_t)(brow0 + (tid >> 2)) * Kdim + st_c * 16;

    auto stageTile = [&](int t) {   // 8 gload_lds16 / thread = full 64 KB tile
        const int base = (t & 1) * 32768;
        const size_t ko = (size_t)t * BK;
#pragma unroll
        for (int ks = 0; ks < 2; ++ks) {
            const char* ga = agp + ko + ks * 64;
            const char* gb = bgp + ko + ks * 64;
            const int lb = base + ks * 16384 + tid * 16;
            gload_lds16(ga,                       &smem[lb]);
            gload_lds16(ga + (size_t)128 * Kdim,  &smem[lb + 8192]);
            gload_lds16(gb,                       &smem[65536 + lb]);
            gload_lds16(gb + (size_t)128 * Kdim,  &smem[65536 + lb + 8192]);
        }
    };
    auto rdA = [&](int buf, int ks, int m) {
        return smem4[buf * 2048 + ks * 1024 + a_rd16 + m * 64];
    };
    auto rdB = [&](int buf, int ks, int n) {
        return smem4[buf * 2048 + ks * 1024 + b_rd16 + n * 64];
    };

    i32x4 acc[8][4] = {};
    i32x4 a0[4], a1[4], b0[4], b1[4];

    // prologue: tiles 0,1 staged; tile 0 proven; preload first frags
    stageTile(0);
    stageTile(1);
    WAITVM(8);
    bar();
    LD_A(a0, 0, 0, 0);
    LD_B(b0, 0, 0);

    for (int t = 0; t < NT; ++t) {
        const int buf = t & 1;
        // fence-free region: frag reads interleave with MFMA stream
        // (compiler-owned counted lgkmcnt; LDS unit drains under matrix pipe)
        LD_A(a1, buf, 0, 4);
        QUAD(0, a0, b0);
        LD_A(a0, buf, 1, 0);
        LD_B(b1, buf, 1);
        QUAD(4, a1, b0);
        LD_A(a1, buf, 1, 4);
        QUAD(0, a0, b1);
        QUAD(4, a1, b1);

        bar();   // all waves' reads of buf returned -> safe to restage it
        if (t + 2 < NT) {
            stageTile(t + 2);   // -> same parity buffer as t
            WAITVM(8);          // proves stage(t+1) landed
        } else {
            WAITVM(0);
        }
        bar();   // tile t+1 visible to all
        if (t + 1 < NT) {
            LD_A(a0, buf ^ 1, 0, 0);
            LD_B(b0, buf ^ 1, 0);
        }
    }

    // ---------------- epilogue: requantize ----------------
    const int qm = *qm_p;
    const int ex = *ex_p;
    const int zp = *zp_p;
    const int rm = (qm < 2147418112) ? ((qm + (1 << 15)) >> 16) : 32767;
    const int shifts = 15 - ex;
    const long long rnd = (shifts > 0) ? (1LL << (shifts - 1)) : 0;

    int bv[4];
#pragma unroll
    for (int n = 0; n < 4; ++n) bv[n] = bias[brow0 + wc * 64 + n * 16 + l15];

#pragma unroll
    for (int m = 0; m < 8; ++m) {
        const int row0 = arow0 + wr * 128 + m * 16 + lks * 4;
#pragma unroll
        for (int n = 0; n < 4; ++n) {
            const int col = brow0 + wc * 64 + n * 16 + l15;
#pragma unroll
            for (int j = 0; j < 4; ++j) {
                long long v = (long long)(acc[m][n][j] + bv[n]) * rm + rnd;
                v >>= shifts;
                v += zp;
                v = v < -128 ? -128 : (v > 127 ? 127 : v);
                out[(size_t)(row0 + j) * Ndim + col] = (int)v;
            }
        }
    }
}

extern "C" void kernel_launch(void* const* d_in, const int* in_sizes, int n_in,
                              void* d_out, int out_size, void* d_ws, size_t ws_size,
                              hipStream_t stream) {
    const int* x32  = (const int*)d_in[0];
    const int* w32  = (const int*)d_in[1];
    const int* bias = (const int*)d_in[2];
    const int* qm   = (const int*)d_in[3];
    const int* ex   = (const int*)d_in[4];
    const int* zp   = (const int*)d_in[5];
    int* out = (int*)d_out;

    char* xa = (char*)d_ws;
    char* wa = xa + (size_t)Bdim * Kdim;
    const int nx16 = Bdim * Kdim / 16;            // 524288
    const int ntot = nx16 + Ndim * Kdim / 16;     // 2621440
    pack_all<<<(ntot + 255) / 256, 256, 0, stream>>>(x32, w32, xa, wa, nx16, ntot);

    const int grid = (Bdim / 256) * (Ndim / 256);   // 256
    gemm22<<<grid, 512, 0, stream>>>(xa, wa, bias, qm, ex, zp, out);
}

// Round 23
// 100.355 us; speedup vs baseline: 1.0559x; 1.0559x over previous
//
#include <hip/hip_runtime.h>

#define DEVI __device__ __forceinline__

typedef int i32x4 __attribute__((ext_vector_type(4)));

static constexpr int Bdim = 2048;
static constexpr int Kdim = 4096;
static constexpr int Ndim = 8192;
static constexpr int BK   = 128;         // int8 k-elements per tile (128 B/row)
static constexpr int NT   = Kdim / BK;   // 32 K-tiles

typedef __attribute__((address_space(1))) const unsigned int gas_t;
typedef __attribute__((address_space(3))) unsigned int las_t;

DEVI void gload_lds16(const void* g, void* l) {
    __builtin_amdgcn_global_load_lds((gas_t*)g, (las_t*)l, 16, 0, 0);
}

DEVI int pack4(i32x4 v) {
    return (v[0] & 255) | ((v[1] & 255) << 8) | ((v[2] & 255) << 16) | (v[3] << 24);
}

// ------------- pack both inputs, one launch (block-aligned split) -------------
// nx16 = 524288 = 2048 blocks * 256 -> blocks 0..2047 pack X, rest pack W.
__global__ void pack_all(const int* __restrict__ x32, const int* __restrict__ w32,
                         char* __restrict__ xa, char* __restrict__ wa,
                         int nx16, int ntot) {
    int i = blockIdx.x * blockDim.x + threadIdx.x;
    if (i >= ntot) return;
    const int* src;
    char* dst;
    if (i < nx16) { src = x32 + (size_t)i * 16;          dst = xa + (size_t)i * 16; }
    else          { src = w32 + (size_t)(i - nx16) * 16; dst = wa + (size_t)(i - nx16) * 16; }
    const i32x4* s4 = (const i32x4*)src;
    i32x4 r;
    r[0] = pack4(s4[0]);
    r[1] = pack4(s4[1]);
    r[2] = pack4(s4[2]);
    r[3] = pack4(s4[3]);
    *(i32x4*)dst = r;
}

// -------- 256x256 i8 GEMM: 2 phases / 2 barriers per K-tile (best measured) --------
#define CFENCE asm volatile("" ::: "memory")
DEVI void bar() { CFENCE; __builtin_amdgcn_s_barrier(); CFENCE; }
#define WAITVM(N) asm volatile("s_waitcnt vmcnt(" #N ")" ::: "memory")
#define PRIO1 __builtin_amdgcn_s_setprio(1)
#define PRIO0 __builtin_amdgcn_s_setprio(0)

#define QUAD(MB, A, B)                                                           \
    do {                                                                         \
        _Pragma("unroll") for (int mm = 0; mm < 4; ++mm)                         \
        _Pragma("unroll") for (int n = 0; n < 4; ++n)                            \
            acc[(MB) + mm][n] = __builtin_amdgcn_mfma_i32_16x16x64_i8(           \
                (A)[mm], (B)[n], acc[(MB) + mm][n], 0, 0, 0);                    \
    } while (0)

// One phase: 12 frag reads (compiler-scheduled counted lgkm), 4 stage-DMAs,
// 32 MFMAs, one barrier. Ring: phase A(t) stages (t+1).ks1 (last read phase
// B(t-1), >=1 bar earlier); phase B(t) stages (t+2).ks0 (last read phase A(t)).
#define PHASE(CUR, KS, STG, VM)                                                  \
    {                                                                            \
        _Pragma("unroll") for (int mm = 0; mm < 8; ++mm) a[mm] = rdA(CUR, KS, mm); \
        _Pragma("unroll") for (int n = 0; n < 4; ++n)    b[n]  = rdB(CUR, KS, n);  \
        STG;                                                                     \
        PRIO1; QUAD(0, a, b); QUAD(4, a + 4, b); PRIO0;                          \
        VM;                                                                      \
        bar();                                                                   \
    }

__attribute__((amdgpu_waves_per_eu(2, 2)))
__global__ __launch_bounds__(512, 2)
void gemm13(const char* __restrict__ A8, const char* __restrict__ B8,
            const int* __restrict__ bias,
            const int* __restrict__ qm_p, const int* __restrict__ ex_p,
            const int* __restrict__ zp_p, int* __restrict__ out) {
    // LDS (16B units): A [2 buf][2 ks][256 rows][4 slots] at 0, B same at 4096
    __shared__ i32x4 smem4[8192];                     // 128 KiB
    char* smem = (char*)smem4;

    const int tid  = threadIdx.x;
    const int wid  = tid >> 6;
    const int lane = tid & 63;
    const int l15  = lane & 15;
    const int lks  = lane >> 4;
    const int wr   = wid >> 2;   // 0..1
    const int wc   = wid & 3;    // 0..3

    // XCD-bijective swizzle (256 % 8 == 0)
    const int bid = blockIdx.x;
    const int swz = (bid & 7) * 32 + (bid >> 3);
    const int bm  = swz >> 5;    // 0..7
    const int bn  = swz & 31;    // 0..31
    const int arow0 = bm * 256;
    const int brow0 = bn * 256;

    // T2 swizzle (r10-verified 0-conflict): phys slot = chunk ^ ((row>>1)&3)
    const int swsel = lks ^ ((l15 >> 1) & 3);
    const int a_rd16 = (wr * 128 + l15) * 4 + swsel;
    const int b_rd16 = 4096 + (wc * 64 + l15) * 4 + swsel;

    // staging: thread covers rows tid>>2 (+128), chunk st_c (inverse swizzle)
    const int st_c = (tid & 3) ^ ((tid >> 3) & 3);
    const char* agp = A8 + (size_t)(arow0 + (tid >> 2)) * Kdim + st_c * 16;
    const char* bgp = B8 + (size_t)(brow0 + (tid >> 2)) * Kdim + st_c * 16;

    auto stage = [&](int isb, int t, int ks) {   // 2 gload_lds16
        const char* gp = (isb ? bgp : agp) + (size_t)t * BK + ks * 64;
        const int lb = (isb ? 65536 : 0) + (t & 1) * 32768 + ks * 16384 + tid * 16;
        gload_lds16(gp, &smem[lb]);
        gload_lds16(gp + (size_t)128 * Kdim, &smem[lb + 8192]);
    };
    auto rdA = [&](int buf, int ks, int m) {
        return smem4[buf * 2048 + ks * 1024 + a_rd16 + m * 64];
    };
    auto rdB = [&](int buf, int ks, int n) {
        return smem4[buf * 2048 + ks * 1024 + b_rd16 + n * 64];
    };

    i32x4 acc[8][4] = {};
    i32x4 a[8], b[4];

    // prologue: tile0.ks0, tile0.ks1, tile1.ks0 (12 DMAs); prove tile 0 (oldest 8)
    stage(0, 0, 0); stage(1, 0, 0);
    stage(0, 0, 1); stage(1, 0, 1);
    stage(0, 1, 0); stage(1, 1, 0);
    WAITVM(4);
    bar();

    int t = 0;
    for (; t < NT - 2; ++t) {
        const int buf = t & 1;
        PHASE(buf, 0, (stage(0, t + 1, 1), stage(1, t + 1, 1)), ((void)0));
        PHASE(buf, 1, (stage(0, t + 2, 0), stage(1, t + 2, 0)), WAITVM(4));
    }
    // t = NT-2: no (t+2) stage; drain phase-A stages fully before t+1 reads
    {
        const int buf = t & 1;
        PHASE(buf, 0, (stage(0, t + 1, 1), stage(1, t + 1, 1)), ((void)0));
        PHASE(buf, 1, ((void)0), WAITVM(0));
    }
    ++t;
    // t = NT-1: pure compute
    {
        const int buf = t & 1;
        PHASE(buf, 0, ((void)0), ((void)0));
        PHASE(buf, 1, ((void)0), ((void)0));
    }

    // ---------------- epilogue: requantize ----------------
    const int qm = *qm_p;
    const int ex = *ex_p;
    const int zp = *zp_p;
    const int rm = (qm < 2147418112) ? ((qm + (1 << 15)) >> 16) : 32767;
    const int shifts = 15 - ex;
    const long long rnd = (shifts > 0) ? (1LL << (shifts - 1)) : 0;

    int bv[4];
#pragma unroll
    for (int n = 0; n < 4; ++n) bv[n] = bias[brow0 + wc * 64 + n * 16 + l15];

#pragma unroll
    for (int m = 0; m < 8; ++m) {
        const int row0 = arow0 + wr * 128 + m * 16 + lks * 4;
#pragma unroll
        for (int n = 0; n < 4; ++n) {
            const int col = brow0 + wc * 64 + n * 16 + l15;
#pragma unroll
            for (int j = 0; j < 4; ++j) {
                long long v = (long long)(acc[m][n][j] + bv[n]) * rm + rnd;
                v >>= shifts;
                v += zp;
                v = v < -128 ? -128 : (v > 127 ? 127 : v);
                out[(size_t)(row0 + j) * Ndim + col] = (int)v;
            }
        }
    }
}

extern "C" void kernel_launch(void* const* d_in, const int* in_sizes, int n_in,
                              void* d_out, int out_size, void* d_ws, size_t ws_size,
                              hipStream_t stream) {
    const int* x32  = (const int*)d_in[0];
    const int* w32  = (const int*)d_in[1];
    const int* bias = (const int*)d_in[2];
    const int* qm   = (const int*)d_in[3];
    const int* ex   = (const int*)d_in[4];
    const int* zp   = (const int*)d_in[5];
    int* out = (int*)d_out;

    char* xa = (char*)d_ws;
    char* wa = xa + (size_t)Bdim * Kdim;
    const int nx16 = Bdim * Kdim / 16;            // 524288 (= 2048 blocks)
    const int ntot = nx16 + Ndim * Kdim / 16;     // 2621440
    pack_all<<<(ntot + 255) / 256, 256, 0, stream>>>(x32, w32, xa, wa, nx16, ntot);

    const int grid = (Bdim / 256) * (Ndim / 256);   // 256
    gemm13<<<grid, 512, 0, stream>>>(xa, wa, bias, qm, ex, zp, out);
}